// Round 11
// baseline (688.088 us; speedup 1.0000x reference)
//
#include <hip/hip_runtime.h>
#include <math.h>

#define N 4096
#define BSZ 2048
#define D 128
#define SH0 300000           // shadow atomic arrays (floats); cf ends ~278560
#define SHS (SH0 + 3 * N)    // per-thread sink area (262144 floats)

typedef __bf16 bf16x8 __attribute__((ext_vector_type(8)));
typedef float f32x4 __attribute__((ext_vector_type(4)));
typedef unsigned short u16x8 __attribute__((ext_vector_type(8)));

__device__ __forceinline__ int rowbase(int i) {
    return (i & (BSZ - 1)) * (2 * D) + (i >> 11) * D;
}
__device__ __forceinline__ unsigned short f2bf(float x) {
    unsigned u = __float_as_uint(x);
    return (unsigned short)((u + 0x7fffu + ((u >> 16) & 1u)) >> 16);  // RNE
}

// ===================== real pipeline (R9 verbatim) =====================
__global__ void init_kernel(const float* __restrict__ feat, float* __restrict__ ws,
                            unsigned short* __restrict__ cf) {
    int t = threadIdx.x;
    int row = blockIdx.x * 16 + (t >> 4);
    int lq = t & 15;
    const float* p = feat + rowbase(row) + lq * 8;
    float4 v0 = *(const float4*)(p);
    float4 v1 = *(const float4*)(p + 4);
    float dot = v0.x * v0.x + v0.y * v0.y + v0.z * v0.z + v0.w * v0.w
              + v1.x * v1.x + v1.y * v1.y + v1.z * v1.z + v1.w * v1.w;
#pragma unroll
    for (int off = 1; off < 16; off <<= 1) dot += __shfl_xor(dot, off);

    u16x8 u;
    u[0] = f2bf(v0.x); u[1] = f2bf(v0.y); u[2] = f2bf(v0.z); u[3] = f2bf(v0.w);
    u[4] = f2bf(v1.x); u[5] = f2bf(v1.y); u[6] = f2bf(v1.z); u[7] = f2bf(v1.w);
    *(u16x8*)(cf + row * D + lq * 8) = u;

    if (lq == 0) {
        ws[row] = fminf(fmaxf(dot, -1.f), 1.f);
        ws[N + row] = 0.f;
        ws[2 * N + row] = 0.f;
        ws[3 * N + row] = 0.f;
    }
    if (blockIdx.x == 0 && t == 0) {
        ws[4 * N] = 0.f;
        ((unsigned int*)ws)[4 * N + 1] = 0u;
    }
}

__launch_bounds__(256)
__global__ void pair_kernel(const unsigned short* __restrict__ cf,
                            const int* __restrict__ labels, float* __restrict__ ws) {
    __shared__ float labIf[128], labJf[128];
    __shared__ float mI[128];

    const int t = threadIdx.x;
    const int bi = blockIdx.x >> 5;
    const int bj = blockIdx.x & 31;
    const int i0 = bi * 128, j0 = bj * 128;

    if (t < 128) {
        labIf[t] = (float)labels[(i0 + t) & (BSZ - 1)];
        mI[t] = ws[i0 + t];
    } else {
        int u = t - 128;
        labJf[u] = (float)labels[(j0 + u) & (BSZ - 1)];
    }
    __syncthreads();

    const int wid = t >> 6, lane = t & 63;
    const int wp = wid >> 1, wq = wid & 1;
    const int lrow = lane & 15, lk = (lane >> 4) * 8;

    const unsigned short* A0 = cf + (size_t)(j0 + wq * 64 + lrow) * D + lk;
    const unsigned short* B0 = cf + (size_t)(i0 + wp * 64 + lrow) * D + lk;

    f32x4 acc[4][4] = {};
#pragma unroll
    for (int ks = 0; ks < 4; ++ks) {
        bf16x8 a[4], b[4];
#pragma unroll
        for (int r = 0; r < 4; ++r) a[r] = *(const bf16x8*)(A0 + r * 16 * D + ks * 32);
#pragma unroll
        for (int c = 0; c < 4; ++c) b[c] = *(const bf16x8*)(B0 + c * 16 * D + ks * 32);
#pragma unroll
        for (int r = 0; r < 4; ++r)
#pragma unroll
            for (int c = 0; c < 4; ++c)
                acc[r][c] = __builtin_amdgcn_mfma_f32_16x16x32_bf16(a[r], b[c], acc[r][c], 0, 0, 0);
    }

    const int jbl = wq * 64 + ((lane >> 4) << 2);
    float lj[16];
#pragma unroll
    for (int ar = 0; ar < 4; ++ar)
#pragma unroll
        for (int rg = 0; rg < 4; ++rg)
            lj[ar * 4 + rg] = labJf[jbl + ar * 16 + rg];

    const bool hasDiag = (bi == bj);

#pragma unroll
    for (int ac = 0; ac < 4; ++ac) {
        const int ri = wp * 64 + ac * 16 + lrow;
        const int gi = i0 + ri;
        const float li = labIf[ri];
        const float m = mI[ri];
        const int dg = hasDiag ? (ri - jbl) : -1;
        float s1 = 0.f, sc = 0.f, ct = 0.f;
#pragma unroll
        for (int ar = 0; ar < 4; ++ar) {
#pragma unroll
            for (int rg = 0; rg < 4; ++rg) {
                float c = __builtin_amdgcn_fmed3f(acc[ar][ac][rg], -1.f, 1.f);
                float distf = li - lj[ar * 4 + rg];
                float rev = fmaf(distf, -0.005f, 0.5f);
                float cph = __builtin_amdgcn_cosf(rev);
                float sph = __builtin_fabsf(__builtin_amdgcn_sinf(rev));
                float st = __builtin_amdgcn_sqrtf(fmaf(-c, c, 1.000001f));
                float nl = fmaf(c, cph, -st * sph);
                bool pos = (distf == 0.f);
                bool diag = (dg == ar * 16 + rg);
                float logit = pos ? (c - m) : nl;
                float e = diag ? 0.f : __expf(logit);
                float pf = (pos && !diag) ? 1.f : 0.f;
                s1 += e;
                sc = fmaf(pf, c, sc);
                ct += pf;
            }
        }
        s1 += __shfl_xor(s1, 16); s1 += __shfl_xor(s1, 32);
        sc += __shfl_xor(sc, 16); sc += __shfl_xor(sc, 32);
        ct += __shfl_xor(ct, 16); ct += __shfl_xor(ct, 32);
        if (lane < 16) {
            atomicAdd(&ws[N + gi], s1);
            atomicAdd(&ws[2 * N + gi], sc);
            atomicAdd(&ws[3 * N + gi], ct);
        }
    }
}

__global__ void final_kernel(float* __restrict__ ws, float* __restrict__ out) {
    __shared__ float red[4];
    const int t = threadIdx.x;
    const int i = blockIdx.x * 256 + t;

    float ct = ws[3 * N + i];
    float lp = ws[2 * N + i] - ct * ws[i] - ct * __logf(ws[N + i]);
    float v = (lp + 1e-6f) / (ct + 1e-6f);
#pragma unroll
    for (int off = 1; off < 64; off <<= 1) v += __shfl_xor(v, off);
    if ((t & 63) == 0) red[t >> 6] = v;
    __syncthreads();

    if (t == 0) {
        float bsum = red[0] + red[1] + red[2] + red[3];
        atomicAdd(&ws[4 * N], bsum);
        __threadfence();
        unsigned int old = atomicAdd(&((unsigned int*)ws)[4 * N + 1], 1u);
        if (old == 15u) {
            float total = __hip_atomic_load(&ws[4 * N], __ATOMIC_ACQUIRE,
                                            __HIP_MEMORY_SCOPE_AGENT);
            out[0] = -total / (float)N;
        }
    }
}

// ===================== ablation kernels (shadow-only writes) =====================
// Phase A: loads + MFMA only, 24 reps (opaque pointer perturbation defeats hoist)
__launch_bounds__(256)
__global__ void abl_mfma(const unsigned short* __restrict__ cf, float* __restrict__ ws) {
    const int t = threadIdx.x;
    const int bi = blockIdx.x >> 5, bj = blockIdx.x & 31;
    const int i0 = bi * 128, j0 = bj * 128;
    const int wid = t >> 6, lane = t & 63;
    const int wp = wid >> 1, wq = wid & 1;
    const int lrow = lane & 15, lk = (lane >> 4) * 8;
    const unsigned short* A0 = cf + (size_t)(j0 + wq * 64 + lrow) * D + lk;
    const unsigned short* B0 = cf + (size_t)(i0 + wp * 64 + lrow) * D + lk;

    f32x4 acc[4][4] = {};
    for (int rep = 0; rep < 24; ++rep) {
        int z = 0; asm volatile("" : "+v"(z));
        const unsigned short* A = A0 + z;
        const unsigned short* B = B0 + z;
#pragma unroll
        for (int ks = 0; ks < 4; ++ks) {
            bf16x8 a[4], b[4];
#pragma unroll
            for (int r = 0; r < 4; ++r) a[r] = *(const bf16x8*)(A + r * 16 * D + ks * 32);
#pragma unroll
            for (int c = 0; c < 4; ++c) b[c] = *(const bf16x8*)(B + c * 16 * D + ks * 32);
#pragma unroll
            for (int r = 0; r < 4; ++r)
#pragma unroll
                for (int c = 0; c < 4; ++c)
                    acc[r][c] = __builtin_amdgcn_mfma_f32_16x16x32_bf16(a[r], b[c], acc[r][c], 0, 0, 0);
        }
    }
    float s = 0.f;
#pragma unroll
    for (int r = 0; r < 4; ++r)
#pragma unroll
        for (int c = 0; c < 4; ++c)
#pragma unroll
            for (int k = 0; k < 4; ++k) s += acc[r][c][k];
    ws[SHS + blockIdx.x * 256 + t] = s;
}

// Phases B/C/D: MODE 1 = epilogue math only; 2 = +shuffle reduce; 3 = +atomics
template <int MODE>
__launch_bounds__(256)
__global__ void abl_epi(const unsigned short* __restrict__ cf,
                        const int* __restrict__ labels, float* __restrict__ ws) {
    __shared__ float labIf[128], labJf[128], mI[128];
    const int t = threadIdx.x;
    const int bi = blockIdx.x >> 5, bj = blockIdx.x & 31;
    const int i0 = bi * 128, j0 = bj * 128;

    if (t < 128) {
        labIf[t] = (float)labels[(i0 + t) & (BSZ - 1)];
        mI[t] = ws[i0 + t];
    } else {
        int u = t - 128;
        labJf[u] = (float)labels[(j0 + u) & (BSZ - 1)];
    }
    __syncthreads();

    const int wid = t >> 6, lane = t & 63;
    const int wp = wid >> 1, wq = wid & 1;
    const int lrow = lane & 15, lk = (lane >> 4) * 8;
    const unsigned short* A0 = cf + (size_t)(j0 + wq * 64 + lrow) * D + lk;
    const unsigned short* B0 = cf + (size_t)(i0 + wp * 64 + lrow) * D + lk;

    f32x4 acc[4][4] = {};
#pragma unroll
    for (int ks = 0; ks < 4; ++ks) {
        bf16x8 a[4], b[4];
#pragma unroll
        for (int r = 0; r < 4; ++r) a[r] = *(const bf16x8*)(A0 + r * 16 * D + ks * 32);
#pragma unroll
        for (int c = 0; c < 4; ++c) b[c] = *(const bf16x8*)(B0 + c * 16 * D + ks * 32);
#pragma unroll
        for (int r = 0; r < 4; ++r)
#pragma unroll
            for (int c = 0; c < 4; ++c)
                acc[r][c] = __builtin_amdgcn_mfma_f32_16x16x32_bf16(a[r], b[c], acc[r][c], 0, 0, 0);
    }

    const int jbl = wq * 64 + ((lane >> 4) << 2);
    float lj[16];
#pragma unroll
    for (int ar = 0; ar < 4; ++ar)
#pragma unroll
        for (int rg = 0; rg < 4; ++rg)
            lj[ar * 4 + rg] = labJf[jbl + ar * 16 + rg];

    const bool hasDiag = (bi == bj);
    float li4[4], m4[4];
    int dg4[4];
#pragma unroll
    for (int ac = 0; ac < 4; ++ac) {
        int ri = wp * 64 + ac * 16 + lrow;
        li4[ac] = labIf[ri];
        m4[ac] = mI[ri];
        dg4[ac] = hasDiag ? (ri - jbl) : -1;
    }

    float sink = 0.f;
    for (int rep = 0; rep < 8; ++rep) {
        float zf = 0.f; asm volatile("" : "+v"(zf));   // opaque 0: defeats cross-rep CSE
#pragma unroll
        for (int ac = 0; ac < 4; ++ac) {
            const int gi = i0 + wp * 64 + ac * 16 + lrow;
            float s1 = 0.f, sc = 0.f, ct = 0.f;
#pragma unroll
            for (int ar = 0; ar < 4; ++ar) {
#pragma unroll
                for (int rg = 0; rg < 4; ++rg) {
                    float c = __builtin_amdgcn_fmed3f(acc[ar][ac][rg] + zf, -1.f, 1.f);
                    float distf = li4[ac] - lj[ar * 4 + rg] + zf;
                    float rev = fmaf(distf, -0.005f, 0.5f);
                    float cph = __builtin_amdgcn_cosf(rev);
                    float sph = __builtin_fabsf(__builtin_amdgcn_sinf(rev));
                    float st = __builtin_amdgcn_sqrtf(fmaf(-c, c, 1.000001f));
                    float nl = fmaf(c, cph, -st * sph);
                    bool pos = (distf == 0.f);
                    bool diag = (dg4[ac] == ar * 16 + rg);
                    float logit = pos ? (c - m4[ac]) : nl;
                    float e = diag ? 0.f : __expf(logit);
                    float pf = (pos && !diag) ? 1.f : 0.f;
                    s1 += e;
                    sc = fmaf(pf, c, sc);
                    ct += pf;
                }
            }
            if (MODE >= 2) {
                s1 += __shfl_xor(s1, 16); s1 += __shfl_xor(s1, 32);
                sc += __shfl_xor(sc, 16); sc += __shfl_xor(sc, 32);
                ct += __shfl_xor(ct, 16); ct += __shfl_xor(ct, 32);
            }
            if (MODE == 3) {
                if (lane < 16) {
                    atomicAdd(&ws[SH0 + gi], s1);
                    atomicAdd(&ws[SH0 + N + gi], sc);
                    atomicAdd(&ws[SH0 + 2 * N + gi], ct);
                }
            } else {
                sink += s1 + sc + ct;
            }
        }
    }
    ws[SHS + blockIdx.x * 256 + t] = sink;
}

extern "C" void kernel_launch(void* const* d_in, const int* in_sizes, int n_in,
                              void* d_out, int out_size, void* d_ws, size_t ws_size,
                              hipStream_t stream) {
    const float* feat = (const float*)d_in[0];
    const int* labels = (const int*)d_in[1];
    float* ws = (float*)d_ws;
    unsigned short* cf = (unsigned short*)((float*)d_ws + 4 * N + 16);
    float* out = (float*)d_out;

    init_kernel<<<N / 16, 256, 0, stream>>>(feat, ws, cf);
    pair_kernel<<<1024, 256, 0, stream>>>(cf, labels, ws);
    final_kernel<<<16, 256, 0, stream>>>(ws, out);

    // diagnostic ablations (shadow-only writes; amplified to crack top-5)
    abl_mfma<<<1024, 256, 0, stream>>>(cf, ws);
    abl_epi<1><<<1024, 256, 0, stream>>>(cf, labels, ws);
    abl_epi<2><<<1024, 256, 0, stream>>>(cf, labels, ws);
    abl_epi<3><<<1024, 256, 0, stream>>>(cf, labels, ws);
}

// Round 12
// 28.852 us; speedup vs baseline: 23.8491x; 23.8491x over previous
//
#include <hip/hip_runtime.h>
#include <math.h>

#define N 4096
#define BSZ 2048
#define D 128

typedef __bf16 bf16x8 __attribute__((ext_vector_type(8)));
typedef float f32x4 __attribute__((ext_vector_type(4)));
typedef unsigned short u16x8 __attribute__((ext_vector_type(8)));

// cf[i] = features[i % bsz, i / bsz, :]  (view-major stacking)
__device__ __forceinline__ int rowbase(int i) {
    return (i & (BSZ - 1)) * (2 * D) + (i >> 11) * D;
}
__device__ __forceinline__ unsigned short f2bf(float x) {
    unsigned u = __float_as_uint(x);
    return (unsigned short)((u + 0x7fffu + ((u >> 16) & 1u)) >> 16);  // RNE
}

// ws layout (floats): m[0..N) S1[N..2N) sumc[2N..3N) cnt[3N..4N)
//                     [4N]=loss accum, [4N+1]=block counter (u32); cf at 4N+16
__global__ void init_kernel(const float* __restrict__ feat, float* __restrict__ ws,
                            unsigned short* __restrict__ cf) {
    int t = threadIdx.x;
    int row = blockIdx.x * 16 + (t >> 4);
    int lq = t & 15;
    const float* p = feat + rowbase(row) + lq * 8;
    float4 v0 = *(const float4*)(p);
    float4 v1 = *(const float4*)(p + 4);
    float dot = v0.x * v0.x + v0.y * v0.y + v0.z * v0.z + v0.w * v0.w
              + v1.x * v1.x + v1.y * v1.y + v1.z * v1.z + v1.w * v1.w;
#pragma unroll
    for (int off = 1; off < 16; off <<= 1) dot += __shfl_xor(dot, off);

    u16x8 u;
    u[0] = f2bf(v0.x); u[1] = f2bf(v0.y); u[2] = f2bf(v0.z); u[3] = f2bf(v0.w);
    u[4] = f2bf(v1.x); u[5] = f2bf(v1.y); u[6] = f2bf(v1.z); u[7] = f2bf(v1.w);
    *(u16x8*)(cf + row * D + lq * 8) = u;

    if (lq == 0) {
        ws[row] = fminf(fmaxf(dot, -1.f), 1.f);  // rowmax = clipped diagonal
        ws[N + row] = 0.f;
        ws[2 * N + row] = 0.f;
        ws[3 * N + row] = 0.f;
    }
    if (blockIdx.x == 0 && t == 0) {
        ws[4 * N] = 0.f;                          // loss accumulator
        ((unsigned int*)ws)[4 * N + 1] = 0u;      // final-block counter
    }
}

// 1024 blocks x 256 threads: 128x128 tiles; LDS-staged K-halves (XOR-swizzled)
__launch_bounds__(256)
__global__ void pair_kernel(const unsigned short* __restrict__ cf,
                            const int* __restrict__ labels, float* __restrict__ ws) {
    __shared__ unsigned short Abuf[128 * 64];   // J-tile K-half, slot = cc ^ (row&7)
    __shared__ unsigned short Bbuf[128 * 64];   // I-tile K-half
    __shared__ float labIf[128], labJf[128], mI[128];

    const int t = threadIdx.x;
    const int bi = blockIdx.x >> 5;   // 32x32 grid of 128x128 tiles
    const int bj = blockIdx.x & 31;
    const int i0 = bi * 128, j0 = bj * 128;

    if (t < 128) {
        labIf[t] = (float)labels[(i0 + t) & (BSZ - 1)];
        mI[t] = ws[i0 + t];
    } else {
        int u = t - 128;
        labJf[u] = (float)labels[(j0 + u) & (BSZ - 1)];
    }

    const int wid = t >> 6, lane = t & 63;
    const int wp = wid >> 1, wq = wid & 1;      // wp: I half, wq: J half
    const int lrow = lane & 15;

    const int srow = t >> 3;        // staging row within 32-row group
    const int scc = t & 7;          // staging col chunk (16B units)

    f32x4 acc[4][4] = {};   // [ar: J fragment][ac: I fragment]

#pragma unroll
    for (int p = 0; p < 2; ++p) {
        // ---- stage K-half p of both tiles (coalesced global -> swizzled LDS) ----
        u16x8 ra[4], rb[4];
#pragma unroll
        for (int it = 0; it < 4; ++it) {
            int row = it * 32 + srow;
            ra[it] = *(const u16x8*)(cf + (size_t)(j0 + row) * D + p * 64 + scc * 8);
            rb[it] = *(const u16x8*)(cf + (size_t)(i0 + row) * D + p * 64 + scc * 8);
        }
        if (p) __syncthreads();     // phase-0 compute must finish before overwrite
#pragma unroll
        for (int it = 0; it < 4; ++it) {
            int row = it * 32 + srow;
            int sl = scc ^ (row & 7);
            *(u16x8*)(Abuf + row * 64 + sl * 8) = ra[it];
            *(u16x8*)(Bbuf + row * 64 + sl * 8) = rb[it];
        }
        __syncthreads();

        // ---- fragments from LDS + MFMA ----
#pragma unroll
        for (int k2 = 0; k2 < 2; ++k2) {
            const int ccf = k2 * 4 + (lane >> 4);
            const int sa = (ccf ^ (lrow & 7)) * 8;   // row&7 == lrow&7 for all frags
            bf16x8 a[4], b[4];
#pragma unroll
            for (int r = 0; r < 4; ++r)
                a[r] = *(const bf16x8*)(Abuf + (wq * 64 + r * 16 + lrow) * 64 + sa);
#pragma unroll
            for (int c = 0; c < 4; ++c)
                b[c] = *(const bf16x8*)(Bbuf + (wp * 64 + c * 16 + lrow) * 64 + sa);
#pragma unroll
            for (int r = 0; r < 4; ++r)
#pragma unroll
                for (int c = 0; c < 4; ++c)
                    acc[r][c] = __builtin_amdgcn_mfma_f32_16x16x32_bf16(a[r], b[c], acc[r][c], 0, 0, 0);
        }
    }

    // per-lane J labels (float): jr_local = wq*64 + ar*16 + (lane>>4)*4 + rg
    const int jbl = wq * 64 + ((lane >> 4) << 2);
    float lj[16];
#pragma unroll
    for (int ar = 0; ar < 4; ++ar)
#pragma unroll
        for (int rg = 0; rg < 4; ++rg)
            lj[ar * 4 + rg] = labJf[jbl + ar * 16 + rg];

    const bool hasDiag = (bi == bj);

#pragma unroll
    for (int ac = 0; ac < 4; ++ac) {
        const int ri = wp * 64 + ac * 16 + lrow;   // I index (lane-local)
        const int gi = i0 + ri;
        const float li = labIf[ri];
        const float m = mI[ri];
        const int dg = hasDiag ? (ri - jbl) : -1;  // diag when dg == ar*16+rg
        float s1 = 0.f, sc = 0.f, ct = 0.f;
#pragma unroll
        for (int ar = 0; ar < 4; ++ar) {
#pragma unroll
            for (int rg = 0; rg < 4; ++rg) {
                float c = __builtin_amdgcn_fmed3f(acc[ar][ac][rg], -1.f, 1.f);
                float distf = li - lj[ar * 4 + rg];
                // phi = (1 - dist/100)*pi rad -> rev = 0.5 - dist/200 in [0.005,0.995]
                float rev = fmaf(distf, -0.005f, 0.5f);
                float cph = __builtin_amdgcn_cosf(rev);
                float sph = __builtin_fabsf(__builtin_amdgcn_sinf(rev));
                float st = __builtin_amdgcn_sqrtf(fmaf(-c, c, 1.000001f));
                float nl = fmaf(c, cph, -st * sph);
                bool pos = (distf == 0.f);
                bool diag = (dg == ar * 16 + rg);
                float logit = pos ? (c - m) : nl;
                float e = diag ? 0.f : __expf(logit);
                float pf = (pos && !diag) ? 1.f : 0.f;
                s1 += e;
                sc = fmaf(pf, c, sc);
                ct += pf;
            }
        }
        // combine the 4 lane-groups that share gi (lane&15): xor 16, then 32
        s1 += __shfl_xor(s1, 16); s1 += __shfl_xor(s1, 32);
        sc += __shfl_xor(sc, 16); sc += __shfl_xor(sc, 32);
        ct += __shfl_xor(ct, 16); ct += __shfl_xor(ct, 32);
        if (lane < 16) {
            atomicAdd(&ws[N + gi], s1);
            atomicAdd(&ws[2 * N + gi], sc);
            atomicAdd(&ws[3 * N + gi], ct);
        }
    }
}

// 16 blocks x 256 threads: one row per thread; last block writes the scalar out
__global__ void final_kernel(float* __restrict__ ws, float* __restrict__ out) {
    __shared__ float red[4];
    const int t = threadIdx.x;
    const int i = blockIdx.x * 256 + t;

    float ct = ws[3 * N + i];
    float lp = ws[2 * N + i] - ct * ws[i] - ct * __logf(ws[N + i]);
    float v = (lp + 1e-6f) / (ct + 1e-6f);
#pragma unroll
    for (int off = 1; off < 64; off <<= 1) v += __shfl_xor(v, off);
    if ((t & 63) == 0) red[t >> 6] = v;
    __syncthreads();

    if (t == 0) {
        float bsum = red[0] + red[1] + red[2] + red[3];
        atomicAdd(&ws[4 * N], bsum);
        __threadfence();
        unsigned int old = atomicAdd(&((unsigned int*)ws)[4 * N + 1], 1u);
        if (old == 15u) {
            float total = __hip_atomic_load(&ws[4 * N], __ATOMIC_ACQUIRE,
                                            __HIP_MEMORY_SCOPE_AGENT);
            out[0] = -total / (float)N;
        }
    }
}

extern "C" void kernel_launch(void* const* d_in, const int* in_sizes, int n_in,
                              void* d_out, int out_size, void* d_ws, size_t ws_size,
                              hipStream_t stream) {
    const float* feat = (const float*)d_in[0];
    const int* labels = (const int*)d_in[1];
    float* ws = (float*)d_ws;
    unsigned short* cf = (unsigned short*)((float*)d_ws + 4 * N + 16);
    float* out = (float*)d_out;

    init_kernel<<<N / 16, 256, 0, stream>>>(feat, ws, cf);
    pair_kernel<<<1024, 256, 0, stream>>>(cf, labels, ws);
    final_kernel<<<16, 256, 0, stream>>>(ws, out);
}